// Round 15
// baseline (16.923 us; speedup 1.0000x reference)
//
#include <hip/hip_runtime.h>
#include <math.h>

#define KOSC 64
#define CHUNK 32
#define TWO_PI_F  6.28318530717958647692f
#define INV2PI_F  0.15915494309189533577f
#define MIN_SLOPE -2.0f
#define MAX_SLOPE  8.0f

typedef _Float16 v8h __attribute__((ext_vector_type(8)));
typedef float    v4f __attribute__((ext_vector_type(4)));

// gfx950 intrinsic (K=32, A/B = 8 x f16, C/D = 4 x f32).
#define MFMA_F16(a, b, c) \
    __builtin_amdgcn_mfma_f32_16x16x32_f16((a), (b), (c), 0, 0, 0)

// ---------------------------------------------------------------------------
// ws layout:
//   [0,    2048): banksF4[128] float4 {f, s, s*off, w}  (0-63 mod, 64-127 car)
//   [2048, 2064): scalars {sig(rev), 1/tmax, dt}
//   [4096, 53248): Mfrag [12 tcg][4 kk][64 lane][8] _Float16 (B-fragment order)
// ---------------------------------------------------------------------------

__device__ __forceinline__ float wave_reduce_max(float v) {
#pragma unroll
    for (int off = 32; off > 0; off >>= 1)
        v = fmaxf(v, __shfl_xor(v, off, 64));
    return v;
}
__device__ __forceinline__ float wave_reduce_sum(float v) {
#pragma unroll
    for (int off = 32; off > 0; off >>= 1)
        v += __shfl_xor(v, off, 64);
    return v;
}

// ---------------------------------------------------------------------------
// ONE fused prep kernel (13 blocks x 256) — unchanged from round 14:
//  block 0, threads 0-127 (2 waves): per-oscillator constants + scalars.
//  blocks 1-12: trig matrix M for column-tile-group tcg = blockIdx.x-1
//    (h = tcg/6 selects the j-half, tc = tcg%6 the quantity tile), RAW input
//    frequencies, hw f32 trig in REVOLUTIONS (|ang| <= 0.34 rev).
//
// M layout (B-fragment order for mfma_f32_16x16x32_f16; lane l holds
// col = l&15, k = kap0 + 8*(l>>4) + i):
//   Mfrag[tcg][kk][l][i],  kap0 = (tc<2 ? 0 : 128) + 32*kk
//   kappa = 2k -> multiplies wb*cos(A_k); 2k+1 -> wb*sin(A_k)
//   j within half: jm = (l&15) - 15 + 16*h   (chunk midpoint at j=15)
// Quantity tiles (per half):
//   tc0: Cm = cos-sum     tc1: Sfm = f*sin-sum     (modulator)
//   tc2: S  = sin-sum     tc3: C  = cos-sum
//   tc4: Sf = f*sin-sum   tc5: Cf = f*cos-sum      (carrier)
// ---------------------------------------------------------------------------
__global__ void prep_kernel(
    const float* __restrict__ t, int T,
    const float* __restrict__ cfq, const float* __restrict__ cwt,
    const float* __restrict__ mfq, const float* __restrict__ mwt,
    const float* __restrict__ po,
    const float* __restrict__ ces, const float* __restrict__ ceo,
    const float* __restrict__ mes, const float* __restrict__ meo,
    float4* __restrict__ banksF4, float* __restrict__ scalars,
    _Float16* __restrict__ Mfrag)
{
    if (blockIdx.x == 0) {
        const int k = threadIdx.x;
        if (k >= 128) return;
        const int bank = k >> 6;
        const int idx  = k & 63;

        const float fq = bank ? cfq[idx] : mfq[idx];
        const float wt = bank ? cwt[idx] : mwt[idx];
        const float sl = bank ? ces[idx] : mes[idx];
        const float of = bank ? ceo[idx] : meo[idx];

        const float mx = wave_reduce_max(wt);
        const float ex = expf(wt - mx);
        const float sm = wave_reduce_sum(ex);
        const float w  = ex / sm;

        const float sg   = 1.0f / (1.0f + expf(-sl));
        const float s    = exp2f(sg * (MAX_SLOPE - MIN_SLOPE) + MIN_SLOPE);
        const float offv = tanhf(of) * 0.5f;

        banksF4[bank * 64 + idx] = make_float4(fq, s, s * offv, w);

        if (k == 0) {
            scalars[0] = 1.0f / (1.0f + expf(-po[0]));  // phase offset, rev
            scalars[1] = 1.0f / t[T - 1];
            scalars[2] = t[1] - t[0];
        }
        return;
    }

    // ----- M-table blocks -----
    const int tcg = blockIdx.x - 1;                // 0..11
    const int h   = tcg / 6;
    const int tc  = tcg % 6;
    const int kk  = threadIdx.x >> 6;              // 0..3
    const int l   = threadIdx.x & 63;
    const int q   = l >> 4, cp = l & 15;
    const float jm  = (float)(cp - 15 + 16 * h);   // j - 15, j in this half
    const float dt  = t[1] - t[0];
    const int kap0 = ((tc < 2) ? 0 : 128) + 32 * kk;

#pragma unroll
    for (int i = 0; i < 8; ++i) {
        const int kap  = kap0 + q * 8 + i;
        const int bank = kap >> 7;
        const int kidx = (kap & 127) >> 1;
        const int part = kap & 1;
        const float f  = bank ? cfq[kidx] : mfq[kidx];   // raw input freq

        const float ang = jm * (f * dt);           // revolutions, |ang|<=0.34
        const float cj = __builtin_amdgcn_cosf(ang);
        const float sj = __builtin_amdgcn_sinf(ang);

        float val = 0.0f;
        if (bank == 0) {
            if      (tc == 0) val = part ? -sj : cj;        // Cm
            else if (tc == 1) val = (part ? cj : sj) * f;   // Sfm
        } else {
            if      (tc == 2) val = part ? cj : sj;         // S
            else if (tc == 3) val = part ? -sj : cj;        // C
            else if (tc == 4) val = (part ? cj : sj) * f;   // Sf
            else if (tc == 5) val = (part ? -sj : cj) * f;  // Cf
        }
        Mfrag[(((tcg * 4 + kk) * 64 + l) << 3) + i] = (_Float16)val;
    }
}

// ---------------------------------------------------------------------------
// Main kernel: block = 512 threads = 8 waves; 64 chunks x 32 samples = 2048
// samples per block; grid = 512 = 2 blocks/CU.
// Phase 1: wave p computes phasors for its 16 oscillators at each lane's
//   chunk midpoint tm = t[chunk*32+15] (exact Dekker + Sterbenz frac + hw
//   trig in revolutions), packed fp16 (wb*cosA, wb*sinA) -> vlds; wave 0
//   also stashes the 64 tm values in LDS for the epilogue. ONE barrier.
// Phase 2 (in-register, TWO PASSES to cap VGPR pressure under the
//   launch_bounds 128-reg budget — round-14 single-pass held A-frags for
//   both banks + 6 accumulators simultaneously, risking scratch spills):
//   pass A (modulator): A-frags k in [0,128), tiles tc0-1 -> accM[2]
//   pass B (carrier):   A-frags k in [128,256), tiles tc2-5 -> accC[4]
//   MFMA order per tile unchanged -> bit-identical results.
// Epilogue: lane owns cells (chunk = 16tr+4q+i, sample = cp+16h); tmc read
//   from LDS (kills 4 scattered global loads); jitter-corrected mod -> one
//   trig pair -> FM rotation -> store.
// ---------------------------------------------------------------------------
__global__ void __launch_bounds__(512, 4) fm_main_kernel(
    const float* __restrict__ t,
    const float4* __restrict__ banksF4,
    const float* __restrict__ scalars,
    const _Float16* __restrict__ Mfrag,
    float* __restrict__ out)
{
    // V rows padded to 132 words (264 halves, 528 B): 16B-aligned half8 loads.
    __shared__ unsigned vlds[64 * 132];   // 33792 B
    __shared__ float    tmlds[64];        // chunk midpoint times

    const int tid  = threadIdx.x;
    const int c    = tid & 63;                                  // lane / chunk
    const int p    = __builtin_amdgcn_readfirstlane(tid >> 6);  // wave 0..7
    const int base = blockIdx.x * 2048;

    const float sig     = scalars[0];
    const float invtmax = scalars[1];
    const float dtf     = scalars[2];

    // ---------------- phase 1: phasors ----------------
    {
        const float tm  = t[base + c * 32 + 15];
        const float tnm = fmaf(tm, invtmax, -0.5f);
        if (p == 0) tmlds[c] = tm;               // stash for epilogue
        const float4* bb = banksF4 + p * 16;     // wave-uniform -> s_load
        uint2* vrow = reinterpret_cast<uint2*>(vlds + c * 132 + p * 16);
#pragma unroll
        for (int i = 0; i < 8; ++i) {
            unsigned pk2[2];
#pragma unroll
            for (int e = 0; e < 2; ++e) {
                const float4 cst = bb[2 * i + e];        // {f, s, s*off, w}
                const float hi  = cst.x * tm;
                const float lo  = fmaf(cst.x, tm, -hi);  // exact residual
                const float rev = (hi - floorf(hi)) + lo + sig;
                const float cA  = __builtin_amdgcn_cosf(rev);
                const float sA  = __builtin_amdgcn_sinf(rev);
                const float a   = fmaf(cst.y, tnm, cst.z);
                const float wb  = __builtin_amdgcn_rsqf(fmaf(a, a, 1.0f)) * cst.w;
                union { _Float16 h[2]; unsigned u; } pk;
                pk.h[0] = (_Float16)(wb * cA);
                pk.h[1] = (_Float16)(wb * sA);
                pk2[e] = pk.u;
            }
            vrow[i] = make_uint2(pk2[0], pk2[1]);        // osc 2i, 2i+1
        }
    }
    __syncthreads();

    // ---------------- phase 2: MFMA, two passes ----------------
    const int tr = p & 3;                    // chunk-tile
    const int h  = p >> 2;                   // j-half
    const int q  = c >> 4, cp = c & 15;

    const _Float16* vh = reinterpret_cast<const _Float16*>(vlds);
    const _Float16* ap = vh + (16 * tr + cp) * 264 + q * 8;
    const _Float16* mbase = Mfrag + (h * 6) * 2048 + c * 8;

    v4f accM[2], accC[4];

    {   // pass A: modulator tiles (tc = 0,1), A-frags k in [0,128)
        v8h A[4];
#pragma unroll
        for (int kk = 0; kk < 4; ++kk)
            A[kk] = *reinterpret_cast<const v8h*>(ap + kk * 32);
#pragma unroll
        for (int tc = 0; tc < 2; ++tc) {
            const _Float16* mp = mbase + tc * 2048;
            v4f a = {0.0f, 0.0f, 0.0f, 0.0f};
#pragma unroll
            for (int kk = 0; kk < 4; ++kk) {
                const v8h b = *reinterpret_cast<const v8h*>(mp + kk * 512);
                a = MFMA_F16(A[kk], b, a);
            }
            accM[tc] = a;
        }
    }
    {   // pass B: carrier tiles (tc = 2..5), A-frags k in [128,256)
        v8h A[4];
#pragma unroll
        for (int kk = 0; kk < 4; ++kk)
            A[kk] = *reinterpret_cast<const v8h*>(ap + 128 + kk * 32);
#pragma unroll
        for (int tc = 0; tc < 4; ++tc) {
            const _Float16* mp = mbase + (2 + tc) * 2048;
            v4f a = {0.0f, 0.0f, 0.0f, 0.0f};
#pragma unroll
            for (int kk = 0; kk < 4; ++kk) {
                const v8h b = *reinterpret_cast<const v8h*>(mp + kk * 512);
                a = MFMA_F16(A[kk], b, a);
            }
            accC[tc] = a;
        }
    }

    // ---------------- epilogue (in registers) ----------------
    const int sj = cp + 16 * h;
#pragma unroll
    for (int i = 0; i < 4; ++i) {
        const int ch  = 16 * tr + 4 * q + i;
        const int off = base + ch * 32;
        const float tmc = tmlds[ch];             // LDS broadcast read
        const float tje = t[off + sj];
        // 2*pi*(t_j - (tm + (j-15)*dt)): f32 rounding jitter, rad per Hz
        const float d2p = TWO_PI_F * fmaf(-(float)(sj - 15), dtf, tje - tmc);

        const float Cm  = accM[0][i], Sfm = accM[1][i];
        const float S   = accC[0][i], Cc  = accC[1][i];
        const float Sf  = accC[2][i], Cf  = accC[3][i];

        const float m    = fmaf(-d2p, Sfm, Cm);          // modulator value
        const float mrev = m * INV2PI_F;
        const float cm = __builtin_amdgcn_cosf(mrev);
        const float sm = __builtin_amdgcn_sinf(mrev);

        const float u = fmaf(cm, S, sm * Cc);
        const float v = fmaf(cm, Cf, -(sm * Sf));
        out[off + sj] = fmaf(d2p, v, u);
    }
}

// ---------------------------------------------------------------------------
extern "C" void kernel_launch(void* const* d_in, const int* in_sizes, int n_in,
                              void* d_out, int out_size, void* d_ws, size_t ws_size,
                              hipStream_t stream) {
    // setup_inputs() order:
    // 0:t 1:carrier_fq 2:carrier_weight 3:mod_fq 4:mod_weight 5:phase_offset
    // 6:carrier_env_slope 7:carrier_env_offset 8:mod_env_slope 9:mod_env_offset
    const float* t   = (const float*)d_in[0];
    const float* cfq = (const float*)d_in[1];
    const float* cw  = (const float*)d_in[2];
    const float* mfq = (const float*)d_in[3];
    const float* mw  = (const float*)d_in[4];
    const float* po  = (const float*)d_in[5];
    const float* ces = (const float*)d_in[6];
    const float* ceo = (const float*)d_in[7];
    const float* mes = (const float*)d_in[8];
    const float* meo = (const float*)d_in[9];
    const int T = in_sizes[0];

    float4*    banksF4 = (float4*)d_ws;
    float*     scalars = (float*)((char*)d_ws + 2048);
    _Float16*  Mfrag   = (_Float16*)((char*)d_ws + 4096);

    // fused prep (block 0: constants; blocks 1-12: M table)
    prep_kernel<<<13, 256, 0, stream>>>(t, T, cfq, cw, mfq, mw, po,
                                        ces, ceo, mes, meo,
                                        banksF4, scalars, Mfrag);

    const int grid = T / 2048;                 // 512 blocks for T = 1<<20
    fm_main_kernel<<<grid, 512, 0, stream>>>(t, banksF4, scalars, Mfrag,
                                             (float*)d_out);
}

// Round 16
// 14.261 us; speedup vs baseline: 1.1867x; 1.1867x over previous
//
#include <hip/hip_runtime.h>
#include <math.h>

#define TWO_PI_F  6.28318530717958647692f
#define INV2PI_F  0.15915494309189533577f
#define MIN_SLOPE -2.0f
#define MAX_SLOPE  8.0f

typedef _Float16 v8h __attribute__((ext_vector_type(8)));
typedef float    v4f __attribute__((ext_vector_type(4)));

// gfx950 intrinsic (K=32, A/B = 8 x f16, C/D = 4 x f32).
#define MFMA_F16(a, b, c) \
    __builtin_amdgcn_mfma_f32_16x16x32_f16((a), (b), (c), 0, 0, 0)

__device__ __forceinline__ float wave_reduce_max(float v) {
#pragma unroll
    for (int off = 32; off > 0; off >>= 1)
        v = fmaxf(v, __shfl_xor(v, off, 64));
    return v;
}
__device__ __forceinline__ float wave_reduce_sum(float v) {
#pragma unroll
    for (int off = 32; off > 0; off >>= 1)
        v += __shfl_xor(v, off, 64);
    return v;
}

union H8 { _Float16 h[8]; v8h v; };

// ---------------------------------------------------------------------------
// SINGLE fused kernel: block = 512 threads = 8 waves; 64 chunks x 32 samples
// = 2048 samples per block; grid = 512.
//
// Stage 0 (waves 0-1): per-oscillator constants {f, s, s*off, w} via per-wave
//   softmax + envelope math -> cbuf (2 KB LDS). Scalars (sig/invtmax/dt)
//   computed redundantly by every lane. Replaces the separate prep kernel —
//   kills one launch + drain and all banksF4 global traffic.
// Phase 1: wave p computes phasors for its 16 oscillators at each lane's
//   chunk midpoint tm = t[chunk*32+15] (exact Dekker + Sterbenz frac + hw
//   trig in revolutions), packed fp16 (wb*cosA, wb*sinA) -> vlds.
// Phase 2: wave p owns (tr = p&3, h = p>>2). A-fragments from vlds
//   (8 x ds_read_b128). B-fragments GENERATED IN REGISTERS: per kk-group the
//   4 oscillators' cos/sin((j-15)*2pi*f*dt) pairs (8 hw-trans, revolutions,
//   |ang| <= 0.34 rev) are shared by all quantity tiles of the bank:
//     mod:     b0 (Cm)  = [cj, -sj]        b1 (Sfm) = [sj*f, cj*f]
//     carrier: b2 (S)   = [sj,  cj]        b3 (C)   = [cj, -sj]
//              b4 (Sf)  = [sj*f, cj*f]     b5 (Cf)  = [cj*f, -(sj*f)]
//   Accumulation order per accumulator (kk ascending) identical to round 15
//   -> bit-identical results. Kills all Mfrag global traffic.
// Epilogue: in registers; lane owns cells (chunk = 16tr+4q+i, sample cp+16h);
//   jitter-corrected mod -> one trig pair -> FM rotation -> store.
// ---------------------------------------------------------------------------
__global__ void __launch_bounds__(512, 4) fm_fused_kernel(
    const float* __restrict__ t,
    const float* __restrict__ cfq, const float* __restrict__ cwt,
    const float* __restrict__ mfq, const float* __restrict__ mwt,
    const float* __restrict__ po,
    const float* __restrict__ ces, const float* __restrict__ ceo,
    const float* __restrict__ mes, const float* __restrict__ meo,
    float* __restrict__ out, int T)
{
    // V rows padded to 132 words (264 halves, 528 B): 16B-aligned half8 loads.
    __shared__ unsigned vlds[64 * 132];   // 33792 B
    __shared__ float4   cbuf[128];        // {f, s, s*off, w}: 0-63 mod, 64-127 car
    __shared__ float    tmlds[64];        // chunk midpoint times

    const int tid  = threadIdx.x;
    const int c    = tid & 63;                                  // lane
    const int p    = __builtin_amdgcn_readfirstlane(tid >> 6);  // wave 0..7
    const int base = blockIdx.x * 2048;

    // scalars (every lane, redundant, cheap)
    const float sig     = 1.0f / (1.0f + expf(-po[0]));  // phase offset, rev
    const float invtmax = 1.0f / t[T - 1];
    const float dtf     = t[1] - t[0];

    // ---------------- stage 0: oscillator constants (waves 0-1) -------------
    if (p < 2) {
        const float fq = p ? cfq[c] : mfq[c];
        const float wt = p ? cwt[c] : mwt[c];
        const float sl = p ? ces[c] : mes[c];
        const float of = p ? ceo[c] : meo[c];

        const float mx = wave_reduce_max(wt);
        const float ex = expf(wt - mx);
        const float sm = wave_reduce_sum(ex);
        const float w  = ex / sm;

        const float sg   = 1.0f / (1.0f + expf(-sl));
        const float s    = exp2f(sg * (MAX_SLOPE - MIN_SLOPE) + MIN_SLOPE);
        const float offv = tanhf(of) * 0.5f;

        cbuf[p * 64 + c] = make_float4(fq, s, s * offv, w);
    }
    __syncthreads();

    // ---------------- phase 1: phasors ----------------
    {
        const float tm  = t[base + c * 32 + 15];
        const float tnm = fmaf(tm, invtmax, -0.5f);
        if (p == 0) tmlds[c] = tm;               // stash for epilogue
        uint2* vrow = reinterpret_cast<uint2*>(vlds + c * 132 + p * 16);
#pragma unroll
        for (int i = 0; i < 8; ++i) {
            unsigned pk2[2];
#pragma unroll
            for (int e = 0; e < 2; ++e) {
                const float4 cst = cbuf[p * 16 + 2 * i + e];  // uniform -> bcast
                const float hi  = cst.x * tm;
                const float lo  = fmaf(cst.x, tm, -hi);       // exact residual
                const float rev = (hi - floorf(hi)) + lo + sig;
                const float cA  = __builtin_amdgcn_cosf(rev);
                const float sA  = __builtin_amdgcn_sinf(rev);
                const float a   = fmaf(cst.y, tnm, cst.z);
                const float wb  = __builtin_amdgcn_rsqf(fmaf(a, a, 1.0f)) * cst.w;
                union { _Float16 h[2]; unsigned u; } pk;
                pk.h[0] = (_Float16)(wb * cA);
                pk.h[1] = (_Float16)(wb * sA);
                pk2[e] = pk.u;
            }
            vrow[i] = make_uint2(pk2[0], pk2[1]);             // osc 2i, 2i+1
        }
    }
    __syncthreads();

    // ---------------- phase 2: MFMA with in-register B-generation -----------
    const int tr = p & 3;                    // chunk-tile
    const int h  = p >> 2;                   // j-half
    const int q  = c >> 4, cp = c & 15;
    const float jm = (float)(cp - 15 + 16 * h);   // j - 15 for this lane's col

    const _Float16* vh = reinterpret_cast<const _Float16*>(vlds);
    const _Float16* ap = vh + (16 * tr + cp) * 264 + q * 8;

    v4f accM[2], accC[4];

    {   // modulator: A-frags k in [0,128); tiles Cm, Sfm
        v8h A[4];
#pragma unroll
        for (int kk = 0; kk < 4; ++kk)
            A[kk] = *reinterpret_cast<const v8h*>(ap + kk * 32);
        accM[0] = (v4f){0.0f, 0.0f, 0.0f, 0.0f};
        accM[1] = (v4f){0.0f, 0.0f, 0.0f, 0.0f};
#pragma unroll
        for (int kk = 0; kk < 4; ++kk) {
            H8 b0, b1;
#pragma unroll
            for (int u = 0; u < 4; ++u) {
                const float f   = cbuf[16 * kk + 4 * q + u].x;
                const float ang = jm * (f * dtf);        // revolutions
                const float cj  = __builtin_amdgcn_cosf(ang);
                const float sj  = __builtin_amdgcn_sinf(ang);
                b0.h[2 * u]     = (_Float16)cj;          // Cm, kappa even
                b0.h[2 * u + 1] = (_Float16)(-sj);       // Cm, kappa odd
                b1.h[2 * u]     = (_Float16)(sj * f);    // Sfm, even
                b1.h[2 * u + 1] = (_Float16)(cj * f);    // Sfm, odd
            }
            accM[0] = MFMA_F16(A[kk], b0.v, accM[0]);
            accM[1] = MFMA_F16(A[kk], b1.v, accM[1]);
        }
    }
    {   // carrier: A-frags k in [128,256); tiles S, C, Sf, Cf
        v8h A[4];
#pragma unroll
        for (int kk = 0; kk < 4; ++kk)
            A[kk] = *reinterpret_cast<const v8h*>(ap + 128 + kk * 32);
#pragma unroll
        for (int i = 0; i < 4; ++i) accC[i] = (v4f){0.0f, 0.0f, 0.0f, 0.0f};
#pragma unroll
        for (int kk = 0; kk < 4; ++kk) {
            H8 b2, b3, b4, b5;
#pragma unroll
            for (int u = 0; u < 4; ++u) {
                const float f   = cbuf[64 + 16 * kk + 4 * q + u].x;
                const float ang = jm * (f * dtf);        // revolutions
                const float cj  = __builtin_amdgcn_cosf(ang);
                const float sj  = __builtin_amdgcn_sinf(ang);
                b2.h[2 * u]     = (_Float16)sj;          // S
                b2.h[2 * u + 1] = (_Float16)cj;
                b3.h[2 * u]     = (_Float16)cj;          // C
                b3.h[2 * u + 1] = (_Float16)(-sj);
                b4.h[2 * u]     = (_Float16)(sj * f);    // Sf
                b4.h[2 * u + 1] = (_Float16)(cj * f);
                b5.h[2 * u]     = (_Float16)(cj * f);    // Cf
                b5.h[2 * u + 1] = (_Float16)(-sj * f);
            }
            accC[0] = MFMA_F16(A[kk], b2.v, accC[0]);
            accC[1] = MFMA_F16(A[kk], b3.v, accC[1]);
            accC[2] = MFMA_F16(A[kk], b4.v, accC[2]);
            accC[3] = MFMA_F16(A[kk], b5.v, accC[3]);
        }
    }

    // ---------------- epilogue (in registers) ----------------
    const int sj = cp + 16 * h;
#pragma unroll
    for (int i = 0; i < 4; ++i) {
        const int ch  = 16 * tr + 4 * q + i;
        const int off = base + ch * 32;
        const float tmc = tmlds[ch];             // LDS broadcast read
        const float tje = t[off + sj];
        // 2*pi*(t_j - (tm + (j-15)*dt)): f32 rounding jitter, rad per Hz
        const float d2p = TWO_PI_F * fmaf(-(float)(sj - 15), dtf, tje - tmc);

        const float Cm  = accM[0][i], Sfm = accM[1][i];
        const float S   = accC[0][i], Cc  = accC[1][i];
        const float Sf  = accC[2][i], Cf  = accC[3][i];

        const float m    = fmaf(-d2p, Sfm, Cm);          // modulator value
        const float mrev = m * INV2PI_F;
        const float cm = __builtin_amdgcn_cosf(mrev);
        const float sm = __builtin_amdgcn_sinf(mrev);

        const float u = fmaf(cm, S, sm * Cc);
        const float v = fmaf(cm, Cf, -(sm * Sf));
        out[off + sj] = fmaf(d2p, v, u);
    }
}

// ---------------------------------------------------------------------------
extern "C" void kernel_launch(void* const* d_in, const int* in_sizes, int n_in,
                              void* d_out, int out_size, void* d_ws, size_t ws_size,
                              hipStream_t stream) {
    // setup_inputs() order:
    // 0:t 1:carrier_fq 2:carrier_weight 3:mod_fq 4:mod_weight 5:phase_offset
    // 6:carrier_env_slope 7:carrier_env_offset 8:mod_env_slope 9:mod_env_offset
    const float* t   = (const float*)d_in[0];
    const float* cfq = (const float*)d_in[1];
    const float* cw  = (const float*)d_in[2];
    const float* mfq = (const float*)d_in[3];
    const float* mw  = (const float*)d_in[4];
    const float* po  = (const float*)d_in[5];
    const float* ces = (const float*)d_in[6];
    const float* ceo = (const float*)d_in[7];
    const float* mes = (const float*)d_in[8];
    const float* meo = (const float*)d_in[9];
    const int T = in_sizes[0];

    // ONE launch: prep fully folded into the main kernel (d_ws unused).
    const int grid = T / 2048;                 // 512 blocks for T = 1<<20
    fm_fused_kernel<<<grid, 512, 0, stream>>>(t, cfq, cw, mfq, mw, po,
                                              ces, ceo, mes, meo,
                                              (float*)d_out, T);
}

// Round 17
// 12.526 us; speedup vs baseline: 1.3511x; 1.1385x over previous
//
#include <hip/hip_runtime.h>
#include <math.h>

#define TWO_PI_F  6.28318530717958647692f
#define INV2PI_F  0.15915494309189533577f
#define MIN_SLOPE -2.0f
#define MAX_SLOPE  8.0f

typedef _Float16 v8h __attribute__((ext_vector_type(8)));
typedef _Float16 h2  __attribute__((ext_vector_type(2)));
typedef float    v4f __attribute__((ext_vector_type(4)));

// gfx950 intrinsic (K=32, A/B = 8 x f16, C/D = 4 x f32).
#define MFMA_F16(a, b, c) \
    __builtin_amdgcn_mfma_f32_16x16x32_f16((a), (b), (c), 0, 0, 0)

__device__ __forceinline__ float wave_reduce_max(float v) {
#pragma unroll
    for (int off = 32; off > 0; off >>= 1)
        v = fmaxf(v, __shfl_xor(v, off, 64));
    return v;
}
__device__ __forceinline__ float wave_reduce_sum(float v) {
#pragma unroll
    for (int off = 32; off > 0; off >>= 1)
        v += __shfl_xor(v, off, 64);
    return v;
}

union H8 { unsigned u[4]; v8h v; };

// packed fp16 multiply (v_pk_mul_f16)
__device__ __forceinline__ unsigned pkmul(unsigned a, unsigned b) {
    union { unsigned u; h2 h; } A, B, R;
    A.u = a; B.u = b;
    R.h = A.h * B.h;
    return R.u;
}
__device__ __forceinline__ unsigned swap16(unsigned x) {
    return (x >> 16) | (x << 16);
}

// ---------------------------------------------------------------------------
// SINGLE fused kernel: block = 512 threads = 8 waves; 64 chunks x 32 samples
// = 2048 samples per block; grid = 512 (2 blocks/CU).
//
// Stage 0 (waves 0-1): per-oscillator constants {f, s, s*off, w} -> cbuf,
//   plus fh16[osc] = packed fp16 (f,f) for the phase-2 pk_mul assembly.
// Phase 1 (all waves, between barriers 1 and 2):
//   (a) phasors: wave p computes its 16 oscillators at each lane's chunk
//       midpoint tm = t[chunk*32+15] (exact Dekker + Sterbenz frac + hw trig
//       in revolutions), packed fp16 (wb*cosA, wb*sinA) -> vlds.
//   (b) COOPERATIVE trig table (kills the 4x redundant B-gen of round 16):
//       wave p = (hg = p>>2, qq = p&3) fills tpair[hg][cp'][osc] =
//       packed fp16 (cos, sin)(jm * (f*dt)) for osc = qq*32 + (lane&3)*8+i,
//       cp' = lane>>2 -- 8 evals (16 trans) per lane vs 64 in round 16.
// Phase 2: wave p owns (tr = p&3, h = p>>2). A-frags from vlds (8 x b128).
//   B-frags ASSEMBLED from tpair/fh16 (uint4 reads + 1-2 pk-ops per word):
//     pair = (cj, sj); sw = swap(pair) = (sj, cj); S = sign-hi mask
//     b0 (Cm) = pair^S          b1 (Sfm) = pk_mul(sw, fh)
//     b2 (S)  = sw              b3 (C)   = pair^S
//     b4 (Sf) = pk_mul(sw, fh)  b5 (Cf)  = pk_mul(pair^S, fh)
//   MFMA order per accumulator identical to round 16.
// Epilogue: in registers; lane owns (chunk = 16tr+4q+i, sample cp+16h);
//   jitter-corrected mod -> one trig pair -> FM rotation -> store.
// ---------------------------------------------------------------------------
__global__ void __launch_bounds__(512, 4) fm_fused_kernel(
    const float* __restrict__ t,
    const float* __restrict__ cfq, const float* __restrict__ cwt,
    const float* __restrict__ mfq, const float* __restrict__ mwt,
    const float* __restrict__ po,
    const float* __restrict__ ces, const float* __restrict__ ceo,
    const float* __restrict__ mes, const float* __restrict__ meo,
    float* __restrict__ out, int T)
{
    // V rows padded to 132 words (264 halves, 528 B): 16B-aligned half8 loads.
    __shared__ unsigned vlds[64 * 132];      // 33792 B
    __shared__ unsigned tpair[2][16][132];   // (cj,sj) fp16 pairs   16896 B
    __shared__ unsigned fh16[128];           // (f,f) fp16 pairs       512 B
    __shared__ float4   cbuf[128];           // {f,s,s*off,w}         2048 B
    __shared__ float    tmlds[64];           // chunk midpoint times   256 B

    const int tid  = threadIdx.x;
    const int c    = tid & 63;                                  // lane
    const int p    = __builtin_amdgcn_readfirstlane(tid >> 6);  // wave 0..7
    const int base = blockIdx.x * 2048;

    // scalars (every lane, redundant, cheap)
    const float sig     = 1.0f / (1.0f + expf(-po[0]));  // phase offset, rev
    const float invtmax = 1.0f / t[T - 1];
    const float dtf     = t[1] - t[0];

    // ---------------- stage 0: oscillator constants (waves 0-1) -------------
    if (p < 2) {
        const float fq = p ? cfq[c] : mfq[c];
        const float wt = p ? cwt[c] : mwt[c];
        const float sl = p ? ces[c] : mes[c];
        const float of = p ? ceo[c] : meo[c];

        const float mx = wave_reduce_max(wt);
        const float ex = expf(wt - mx);
        const float sm = wave_reduce_sum(ex);
        const float w  = ex / sm;

        const float sg   = 1.0f / (1.0f + expf(-sl));
        const float s    = exp2f(sg * (MAX_SLOPE - MIN_SLOPE) + MIN_SLOPE);
        const float offv = tanhf(of) * 0.5f;

        cbuf[p * 64 + c] = make_float4(fq, s, s * offv, w);

        union { _Float16 h[2]; unsigned u; } fp;
        fp.h[0] = (_Float16)fq;
        fp.h[1] = (_Float16)fq;
        fh16[p * 64 + c] = fp.u;
    }
    __syncthreads();

    // ---------------- phase 1a: phasors ----------------
    {
        const float tm  = t[base + c * 32 + 15];
        const float tnm = fmaf(tm, invtmax, -0.5f);
        if (p == 0) tmlds[c] = tm;               // stash for epilogue
        uint2* vrow = reinterpret_cast<uint2*>(vlds + c * 132 + p * 16);
#pragma unroll
        for (int i = 0; i < 8; ++i) {
            unsigned pk2[2];
#pragma unroll
            for (int e = 0; e < 2; ++e) {
                const float4 cst = cbuf[p * 16 + 2 * i + e];  // uniform -> bcast
                const float hi  = cst.x * tm;
                const float lo  = fmaf(cst.x, tm, -hi);       // exact residual
                const float rev = (hi - floorf(hi)) + lo + sig;
                const float cA  = __builtin_amdgcn_cosf(rev);
                const float sA  = __builtin_amdgcn_sinf(rev);
                const float a   = fmaf(cst.y, tnm, cst.z);
                const float wb  = __builtin_amdgcn_rsqf(fmaf(a, a, 1.0f)) * cst.w;
                union { _Float16 h[2]; unsigned u; } pk;
                pk.h[0] = (_Float16)(wb * cA);
                pk.h[1] = (_Float16)(wb * sA);
                pk2[e] = pk.u;
            }
            vrow[i] = make_uint2(pk2[0], pk2[1]);             // osc 2i, 2i+1
        }
    }

    // ---------------- phase 1b: cooperative trig table ----------------
    {
        const int hg  = p >> 2;                  // which j-half this wave fills
        const int qq  = p & 3;                   // which osc quarter
        const int cpg = c >> 2;                  // jm row
        const int og  = c & 3;                   // osc sub-block
        const float jmg = (float)(cpg - 15 + 16 * hg);
#pragma unroll
        for (int i = 0; i < 8; ++i) {
            const int osc  = qq * 32 + og * 8 + i;
            const float f  = cbuf[osc].x;
            const float ang = jmg * (f * dtf);   // revolutions, |ang|<=0.34
            const float cj = __builtin_amdgcn_cosf(ang);
            const float sj = __builtin_amdgcn_sinf(ang);
            union { _Float16 h[2]; unsigned u; } pk;
            pk.h[0] = (_Float16)cj;
            pk.h[1] = (_Float16)sj;
            tpair[hg][cpg][osc] = pk.u;
        }
    }
    __syncthreads();

    // ---------------- phase 2: MFMA with LDS-assembled B --------------------
    const int tr = p & 3;                    // chunk-tile
    const int h  = p >> 2;                   // j-half
    const int q  = c >> 4, cp = c & 15;
    const unsigned S = 0x80000000u;          // sign of hi (sin) half

    const _Float16* vh = reinterpret_cast<const _Float16*>(vlds);
    const _Float16* ap = vh + (16 * tr + cp) * 264 + q * 8;

    v4f accM[2], accC[4];

    {   // modulator: A-frags k in [0,128); tiles Cm, Sfm
        v8h A[4];
#pragma unroll
        for (int kk = 0; kk < 4; ++kk)
            A[kk] = *reinterpret_cast<const v8h*>(ap + kk * 32);
        accM[0] = (v4f){0.0f, 0.0f, 0.0f, 0.0f};
        accM[1] = (v4f){0.0f, 0.0f, 0.0f, 0.0f};
#pragma unroll
        for (int kk = 0; kk < 4; ++kk) {
            const uint4 pr = *reinterpret_cast<const uint4*>(
                &tpair[h][cp][16 * kk + 4 * q]);
            const uint4 fh = *reinterpret_cast<const uint4*>(
                &fh16[16 * kk + 4 * q]);
            H8 b0, b1;
            const unsigned prw[4] = {pr.x, pr.y, pr.z, pr.w};
            const unsigned fhw[4] = {fh.x, fh.y, fh.z, fh.w};
#pragma unroll
            for (int u = 0; u < 4; ++u) {
                b0.u[u] = prw[u] ^ S;                    // (cj, -sj)
                b1.u[u] = pkmul(swap16(prw[u]), fhw[u]); // (sj*f, cj*f)
            }
            accM[0] = MFMA_F16(A[kk], b0.v, accM[0]);
            accM[1] = MFMA_F16(A[kk], b1.v, accM[1]);
        }
    }
    {   // carrier: A-frags k in [128,256); tiles S, C, Sf, Cf
        v8h A[4];
#pragma unroll
        for (int kk = 0; kk < 4; ++kk)
            A[kk] = *reinterpret_cast<const v8h*>(ap + 128 + kk * 32);
#pragma unroll
        for (int i = 0; i < 4; ++i) accC[i] = (v4f){0.0f, 0.0f, 0.0f, 0.0f};
#pragma unroll
        for (int kk = 0; kk < 4; ++kk) {
            const uint4 pr = *reinterpret_cast<const uint4*>(
                &tpair[h][cp][64 + 16 * kk + 4 * q]);
            const uint4 fh = *reinterpret_cast<const uint4*>(
                &fh16[64 + 16 * kk + 4 * q]);
            H8 b2, b3, b4, b5;
            const unsigned prw[4] = {pr.x, pr.y, pr.z, pr.w};
            const unsigned fhw[4] = {fh.x, fh.y, fh.z, fh.w};
#pragma unroll
            for (int u = 0; u < 4; ++u) {
                const unsigned sw = swap16(prw[u]);      // (sj, cj)
                const unsigned ng = prw[u] ^ S;          // (cj, -sj)
                b2.u[u] = sw;                            // S
                b3.u[u] = ng;                            // C
                b4.u[u] = pkmul(sw, fhw[u]);             // (sj*f, cj*f)
                b5.u[u] = pkmul(ng, fhw[u]);             // (cj*f, -sj*f)
            }
            accC[0] = MFMA_F16(A[kk], b2.v, accC[0]);
            accC[1] = MFMA_F16(A[kk], b3.v, accC[1]);
            accC[2] = MFMA_F16(A[kk], b4.v, accC[2]);
            accC[3] = MFMA_F16(A[kk], b5.v, accC[3]);
        }
    }

    // ---------------- epilogue (in registers) ----------------
    const int sj = cp + 16 * h;
#pragma unroll
    for (int i = 0; i < 4; ++i) {
        const int ch  = 16 * tr + 4 * q + i;
        const int off = base + ch * 32;
        const float tmc = tmlds[ch];             // LDS broadcast read
        const float tje = t[off + sj];
        // 2*pi*(t_j - (tm + (j-15)*dt)): f32 rounding jitter, rad per Hz
        const float d2p = TWO_PI_F * fmaf(-(float)(sj - 15), dtf, tje - tmc);

        const float Cm  = accM[0][i], Sfm = accM[1][i];
        const float Sv  = accC[0][i], Cc  = accC[1][i];
        const float Sf  = accC[2][i], Cf  = accC[3][i];

        const float m    = fmaf(-d2p, Sfm, Cm);          // modulator value
        const float mrev = m * INV2PI_F;
        const float cm = __builtin_amdgcn_cosf(mrev);
        const float sm = __builtin_amdgcn_sinf(mrev);

        const float u = fmaf(cm, Sv, sm * Cc);
        const float v = fmaf(cm, Cf, -(sm * Sf));
        out[off + sj] = fmaf(d2p, v, u);
    }
}

// ---------------------------------------------------------------------------
extern "C" void kernel_launch(void* const* d_in, const int* in_sizes, int n_in,
                              void* d_out, int out_size, void* d_ws, size_t ws_size,
                              hipStream_t stream) {
    // setup_inputs() order:
    // 0:t 1:carrier_fq 2:carrier_weight 3:mod_fq 4:mod_weight 5:phase_offset
    // 6:carrier_env_slope 7:carrier_env_offset 8:mod_env_slope 9:mod_env_offset
    const float* t   = (const float*)d_in[0];
    const float* cfq = (const float*)d_in[1];
    const float* cw  = (const float*)d_in[2];
    const float* mfq = (const float*)d_in[3];
    const float* mw  = (const float*)d_in[4];
    const float* po  = (const float*)d_in[5];
    const float* ces = (const float*)d_in[6];
    const float* ceo = (const float*)d_in[7];
    const float* mes = (const float*)d_in[8];
    const float* meo = (const float*)d_in[9];
    const int T = in_sizes[0];

    // ONE launch: everything fused (d_ws unused).
    const int grid = T / 2048;                 // 512 blocks for T = 1<<20
    fm_fused_kernel<<<grid, 512, 0, stream>>>(t, cfq, cw, mfq, mw, po,
                                              ces, ceo, mes, meo,
                                              (float*)d_out, T);
}

// Round 19
// 12.281 us; speedup vs baseline: 1.3780x; 1.0200x over previous
//
#include <hip/hip_runtime.h>
#include <math.h>

#define TWO_PI_F  6.28318530717958647692f
#define INV2PI_F  0.15915494309189533577f
#define MIN_SLOPE -2.0f
#define MAX_SLOPE  8.0f

typedef _Float16 v8h __attribute__((ext_vector_type(8)));
typedef _Float16 h2  __attribute__((ext_vector_type(2)));
typedef __fp16   fp16x2 __attribute__((ext_vector_type(2)));  // cvt_pkrtz return type
typedef float    v4f __attribute__((ext_vector_type(4)));

// gfx950 intrinsic (K=32, A/B = 8 x f16, C/D = 4 x f32).
#define MFMA_F16(a, b, c) \
    __builtin_amdgcn_mfma_f32_16x16x32_f16((a), (b), (c), 0, 0, 0)

__device__ __forceinline__ float wave_reduce_max(float v) {
#pragma unroll
    for (int off = 32; off > 0; off >>= 1)
        v = fmaxf(v, __shfl_xor(v, off, 64));
    return v;
}
__device__ __forceinline__ float wave_reduce_sum(float v) {
#pragma unroll
    for (int off = 32; off > 0; off >>= 1)
        v += __shfl_xor(v, off, 64);
    return v;
}

union H8 { unsigned u[4]; v8h v; };

// single-instruction packed f32->2xf16 convert (v_cvt_pkrtz_f16_f32).
// NOTE: the builtin returns __fp16 ext_vector(2), not _Float16 (round-18 fix).
__device__ __forceinline__ unsigned pkrtz(float a, float b) {
    union { fp16x2 h; unsigned u; } cv;
    cv.h = __builtin_amdgcn_cvt_pkrtz(a, b);
    return cv.u;
}
// packed fp16 multiply (v_pk_mul_f16)
__device__ __forceinline__ unsigned pkmul(unsigned a, unsigned b) {
    union { unsigned u; h2 h; } A, B, R;
    A.u = a; B.u = b;
    R.h = A.h * B.h;
    return R.u;
}
__device__ __forceinline__ unsigned swap16(unsigned x) {
    return (x >> 16) | (x << 16);
}

// ---------------------------------------------------------------------------
// SINGLE fused kernel: block = 512 threads = 8 waves; 64 chunks x 32 samples
// = 2048 samples per block; grid = 512 (2 blocks/CU).
//
// Latency-overlap structure (round 18/19):
//   - tm = t[chunk*32+15] is loaded BEFORE stage 0 so its HBM latency hides
//     under the softmax/envelope math.
//   - the epilogue's 4 scattered t loads are ISSUED right after barrier 2,
//     before the MFMA cluster, and consumed after it.
// Stage 0 (waves 0-1): per-oscillator constants {f, s, s*off, w} -> cbuf,
//   fh16[osc] = packed fp16 (f,f), fdt[osc] = f*dt.
// Phase 1a: wave p computes phasors for its 16 oscillators at each lane's
//   chunk midpoint tm (exact Dekker + Sterbenz frac + hw trig in
//   revolutions), packed fp16 (wb*cosA, wb*sinA) via cvt_pkrtz -> vlds.
// Phase 1b: cooperative trig table: wave p = (hg = p>>2, qq = p&3) fills
//   tpair[hg][cp'][osc] = packed fp16 (cos, sin)(jm * f*dt), 8 evals/lane.
// Phase 2: wave p owns (tr = p&3, h = p>>2). A-frags from vlds (8 x b128).
//   B-frags assembled from tpair/fh16 (uint4 reads + 1-2 pk-ops per word):
//     pair = (cj, sj); sw = swap(pair); S = sign-hi mask
//     b0 (Cm) = pair^S          b1 (Sfm) = pk_mul(sw, fh)
//     b2 (S)  = sw              b3 (C)   = pair^S
//     b4 (Sf) = pk_mul(sw, fh)  b5 (Cf)  = pk_mul(pair^S, fh)
// Epilogue: in registers; lane owns (chunk = 16tr+4q+i, sample cp+16h);
//   jitter-corrected mod -> one trig pair -> FM rotation -> store.
// ---------------------------------------------------------------------------
__global__ void __launch_bounds__(512, 4) fm_fused_kernel(
    const float* __restrict__ t,
    const float* __restrict__ cfq, const float* __restrict__ cwt,
    const float* __restrict__ mfq, const float* __restrict__ mwt,
    const float* __restrict__ po,
    const float* __restrict__ ces, const float* __restrict__ ceo,
    const float* __restrict__ mes, const float* __restrict__ meo,
    float* __restrict__ out, int T)
{
    // V rows padded to 132 words (264 halves, 528 B): 16B-aligned half8 loads.
    __shared__ unsigned vlds[64 * 132];      // 33792 B
    __shared__ unsigned tpair[2][16][132];   // (cj,sj) fp16 pairs   16896 B
    __shared__ unsigned fh16[128];           // (f,f) fp16 pairs       512 B
    __shared__ float    fdt[128];            // f*dt                   512 B
    __shared__ float4   cbuf[128];           // {f,s,s*off,w}         2048 B
    __shared__ float    tmlds[64];           // chunk midpoint times   256 B

    const int tid  = threadIdx.x;
    const int c    = tid & 63;                                  // lane
    const int p    = __builtin_amdgcn_readfirstlane(tid >> 6);  // wave 0..7
    const int base = blockIdx.x * 2048;

    // scalars (every lane, redundant, cheap)
    const float sig     = 1.0f / (1.0f + expf(-po[0]));  // phase offset, rev
    const float invtmax = 1.0f / t[T - 1];
    const float dtf     = t[1] - t[0];

    // ---- chunk-midpoint time: issued EARLY so HBM latency hides under
    //      stage 0's softmax/envelope math ----
    const float tm  = t[base + c * 32 + 15];
    const float tnm = fmaf(tm, invtmax, -0.5f);
    if (p == 0) tmlds[c] = tm;               // stash for epilogue

    // ---------------- stage 0: oscillator constants (waves 0-1) -------------
    if (p < 2) {
        const float fq = p ? cfq[c] : mfq[c];
        const float wt = p ? cwt[c] : mwt[c];
        const float sl = p ? ces[c] : mes[c];
        const float of = p ? ceo[c] : meo[c];

        const float mx = wave_reduce_max(wt);
        const float ex = expf(wt - mx);
        const float sm = wave_reduce_sum(ex);
        const float w  = ex / sm;

        const float sg   = 1.0f / (1.0f + expf(-sl));
        const float s    = exp2f(sg * (MAX_SLOPE - MIN_SLOPE) + MIN_SLOPE);
        const float offv = tanhf(of) * 0.5f;

        cbuf[p * 64 + c] = make_float4(fq, s, s * offv, w);
        fh16[p * 64 + c] = pkrtz(fq, fq);
        fdt [p * 64 + c] = fq * dtf;
    }
    __syncthreads();

    // ---------------- phase 1a: phasors ----------------
    {
        uint2* vrow = reinterpret_cast<uint2*>(vlds + c * 132 + p * 16);
#pragma unroll
        for (int i = 0; i < 8; ++i) {
            unsigned pk2[2];
#pragma unroll
            for (int e = 0; e < 2; ++e) {
                const float4 cst = cbuf[p * 16 + 2 * i + e];  // uniform -> bcast
                const float hi  = cst.x * tm;
                const float lo  = fmaf(cst.x, tm, -hi);       // exact residual
                const float rev = (hi - floorf(hi)) + lo + sig;
                const float cA  = __builtin_amdgcn_cosf(rev);
                const float sA  = __builtin_amdgcn_sinf(rev);
                const float a   = fmaf(cst.y, tnm, cst.z);
                const float wb  = __builtin_amdgcn_rsqf(fmaf(a, a, 1.0f)) * cst.w;
                pk2[e] = pkrtz(wb * cA, wb * sA);
            }
            vrow[i] = make_uint2(pk2[0], pk2[1]);             // osc 2i, 2i+1
        }
    }

    // ---------------- phase 1b: cooperative trig table ----------------
    {
        const int hg  = p >> 2;                  // which j-half this wave fills
        const int qq  = p & 3;                   // which osc quarter
        const int cpg = c >> 2;                  // jm row
        const int og  = c & 3;                   // osc sub-block
        const float jmg = (float)(cpg - 15 + 16 * hg);
#pragma unroll
        for (int i = 0; i < 8; ++i) {
            const int osc  = qq * 32 + og * 8 + i;
            const float ang = jmg * fdt[osc];    // revolutions, |ang|<=0.34
            const float cj = __builtin_amdgcn_cosf(ang);
            const float sj = __builtin_amdgcn_sinf(ang);
            tpair[hg][cpg][osc] = pkrtz(cj, sj);
        }
    }
    __syncthreads();

    // ---------------- phase 2: MFMA with LDS-assembled B --------------------
    const int tr = p & 3;                    // chunk-tile
    const int h  = p >> 2;                   // j-half
    const int q  = c >> 4, cp = c & 15;
    const int sj = cp + 16 * h;
    const unsigned S = 0x80000000u;          // sign of hi (sin) half

    // issue the epilogue's scattered t loads NOW -- their ~500-cycle HBM/L2
    // latency hides under the MFMA + B-assembly cluster below.
    float tje[4];
#pragma unroll
    for (int i = 0; i < 4; ++i)
        tje[i] = t[base + (16 * tr + 4 * q + i) * 32 + sj];

    const _Float16* vh = reinterpret_cast<const _Float16*>(vlds);
    const _Float16* ap = vh + (16 * tr + cp) * 264 + q * 8;

    v4f accM[2], accC[4];

    {   // modulator: A-frags k in [0,128); tiles Cm, Sfm
        v8h A[4];
#pragma unroll
        for (int kk = 0; kk < 4; ++kk)
            A[kk] = *reinterpret_cast<const v8h*>(ap + kk * 32);
        accM[0] = (v4f){0.0f, 0.0f, 0.0f, 0.0f};
        accM[1] = (v4f){0.0f, 0.0f, 0.0f, 0.0f};
#pragma unroll
        for (int kk = 0; kk < 4; ++kk) {
            const uint4 pr = *reinterpret_cast<const uint4*>(
                &tpair[h][cp][16 * kk + 4 * q]);
            const uint4 fh = *reinterpret_cast<const uint4*>(
                &fh16[16 * kk + 4 * q]);
            H8 b0, b1;
            const unsigned prw[4] = {pr.x, pr.y, pr.z, pr.w};
            const unsigned fhw[4] = {fh.x, fh.y, fh.z, fh.w};
#pragma unroll
            for (int u = 0; u < 4; ++u) {
                b0.u[u] = prw[u] ^ S;                    // (cj, -sj)
                b1.u[u] = pkmul(swap16(prw[u]), fhw[u]); // (sj*f, cj*f)
            }
            accM[0] = MFMA_F16(A[kk], b0.v, accM[0]);
            accM[1] = MFMA_F16(A[kk], b1.v, accM[1]);
        }
    }
    {   // carrier: A-frags k in [128,256); tiles S, C, Sf, Cf
        v8h A[4];
#pragma unroll
        for (int kk = 0; kk < 4; ++kk)
            A[kk] = *reinterpret_cast<const v8h*>(ap + 128 + kk * 32);
#pragma unroll
        for (int i = 0; i < 4; ++i) accC[i] = (v4f){0.0f, 0.0f, 0.0f, 0.0f};
#pragma unroll
        for (int kk = 0; kk < 4; ++kk) {
            const uint4 pr = *reinterpret_cast<const uint4*>(
                &tpair[h][cp][64 + 16 * kk + 4 * q]);
            const uint4 fh = *reinterpret_cast<const uint4*>(
                &fh16[64 + 16 * kk + 4 * q]);
            H8 b2, b3, b4, b5;
            const unsigned prw[4] = {pr.x, pr.y, pr.z, pr.w};
            const unsigned fhw[4] = {fh.x, fh.y, fh.z, fh.w};
#pragma unroll
            for (int u = 0; u < 4; ++u) {
                const unsigned sw = swap16(prw[u]);      // (sj, cj)
                const unsigned ng = prw[u] ^ S;          // (cj, -sj)
                b2.u[u] = sw;                            // S
                b3.u[u] = ng;                            // C
                b4.u[u] = pkmul(sw, fhw[u]);             // (sj*f, cj*f)
                b5.u[u] = pkmul(ng, fhw[u]);             // (cj*f, -sj*f)
            }
            accC[0] = MFMA_F16(A[kk], b2.v, accC[0]);
            accC[1] = MFMA_F16(A[kk], b3.v, accC[1]);
            accC[2] = MFMA_F16(A[kk], b4.v, accC[2]);
            accC[3] = MFMA_F16(A[kk], b5.v, accC[3]);
        }
    }

    // ---------------- epilogue (in registers) ----------------
#pragma unroll
    for (int i = 0; i < 4; ++i) {
        const int ch  = 16 * tr + 4 * q + i;
        const int off = base + ch * 32;
        const float tmc = tmlds[ch];             // LDS broadcast read
        // 2*pi*(t_j - (tm + (j-15)*dt)): f32 rounding jitter, rad per Hz
        const float d2p = TWO_PI_F * fmaf(-(float)(sj - 15), dtf, tje[i] - tmc);

        const float Cm  = accM[0][i], Sfm = accM[1][i];
        const float Sv  = accC[0][i], Cc  = accC[1][i];
        const float Sf  = accC[2][i], Cf  = accC[3][i];

        const float m    = fmaf(-d2p, Sfm, Cm);          // modulator value
        const float mrev = m * INV2PI_F;
        const float cm = __builtin_amdgcn_cosf(mrev);
        const float sm = __builtin_amdgcn_sinf(mrev);

        const float u = fmaf(cm, Sv, sm * Cc);
        const float v = fmaf(cm, Cf, -(sm * Sf));
        out[off + sj] = fmaf(d2p, v, u);
    }
}

// ---------------------------------------------------------------------------
extern "C" void kernel_launch(void* const* d_in, const int* in_sizes, int n_in,
                              void* d_out, int out_size, void* d_ws, size_t ws_size,
                              hipStream_t stream) {
    // setup_inputs() order:
    // 0:t 1:carrier_fq 2:carrier_weight 3:mod_fq 4:mod_weight 5:phase_offset
    // 6:carrier_env_slope 7:carrier_env_offset 8:mod_env_slope 9:mod_env_offset
    const float* t   = (const float*)d_in[0];
    const float* cfq = (const float*)d_in[1];
    const float* cw  = (const float*)d_in[2];
    const float* mfq = (const float*)d_in[3];
    const float* mw  = (const float*)d_in[4];
    const float* po  = (const float*)d_in[5];
    const float* ces = (const float*)d_in[6];
    const float* ceo = (const float*)d_in[7];
    const float* mes = (const float*)d_in[8];
    const float* meo = (const float*)d_in[9];
    const int T = in_sizes[0];

    // ONE launch: everything fused (d_ws unused).
    const int grid = T / 2048;                 // 512 blocks for T = 1<<20
    fm_fused_kernel<<<grid, 512, 0, stream>>>(t, cfq, cw, mfq, mw, po,
                                              ces, ceo, mes, meo,
                                              (float*)d_out, T);
}